// Round 2
// baseline (186.664 us; speedup 1.0000x reference)
//
#include <hip/hip_runtime.h>
#include <stdint.h>

#define Bb 2
#define Tt 2048
#define Cc 1024
#define Hh 16
#define HD 64
#define C3 3072

typedef __bf16 bf16x8 __attribute__((ext_vector_type(8)));
typedef float  f32x4  __attribute__((ext_vector_type(4)));
typedef unsigned short u16;
typedef u16 u16x8 __attribute__((ext_vector_type(8)));
typedef u16 u16x4 __attribute__((ext_vector_type(4)));

#define SCALE2 0.18033688f  /* 1/sqrt(64) * log2(e) */

__device__ __forceinline__ u16 f2bf(float f) {
  union { float f; unsigned u; } v; v.f = f;
  return (u16)((v.u + 0x7fffu + ((v.u >> 16) & 1u)) >> 16);  // RNE
}
__device__ __forceinline__ float bf2f(u16 a) {
  union { unsigned u; float f; } v; v.u = ((unsigned)a) << 16; return v.f;
}

// async global->LDS, 16B per lane. LDS dest = wave-uniform base + lane*16.
__device__ __forceinline__ void gl2lds16(const void* g, void* s) {
  __builtin_amdgcn_global_load_lds(
      (__attribute__((address_space(1))) void*)(g),
      (__attribute__((address_space(3))) void*)(s), 16, 0, 0);
}

__device__ __forceinline__ bf16x8 ldb8(const u16* p) {
  return __builtin_bit_cast(bf16x8, *(const u16x8*)p);
}

// ---------------- merged prep: cvt_x + w_attn^T + w_proj^T ----------------
__global__ __launch_bounds__(256)
void prep_kernel(const float* __restrict__ x, const float* __restrict__ w_attn,
                 const float* __restrict__ w_proj, u16* __restrict__ xb,
                 u16* __restrict__ wat, u16* __restrict__ wpt) {
  __shared__ u16 tile[64][65];
  const int blk = blockIdx.x;
  const int tid = threadIdx.x;
  if (blk < 4096) {
    int i = blk * 256 + tid;
    float4 v = ((const float4*)x)[i];
    u16x4 o = { f2bf(v.x), f2bf(v.y), f2bf(v.z), f2bf(v.w) };
    ((u16x4*)xb)[i] = o;
    return;
  }
  const float* in; u16* out; int R, C, c0, r0;
  if (blk < 4096 + 768) {
    int t = blk - 4096;
    in = w_attn; out = wat; R = 1024; C = 3072;
    c0 = (t % 48) * 64; r0 = (t / 48) * 64;
  } else {
    int t = blk - 4864;
    in = w_proj; out = wpt; R = 1024; C = 1024;
    c0 = (t & 15) * 64; r0 = (t >> 4) * 64;
  }
  int xx = tid & 63, yy = tid >> 6;
  #pragma unroll
  for (int rr = yy; rr < 64; rr += 4)
    tile[rr][xx] = f2bf(in[(size_t)(r0 + rr) * C + c0 + xx]);
  __syncthreads();
  #pragma unroll
  for (int rr = yy; rr < 64; rr += 4)
    out[(size_t)(c0 + rr) * R + r0 + xx] = tile[xx][rr];
}

// ---------------- bf16 GEMM: C[M][N] = A[M][K] * Bt[N][K]^T + bias ----------------
// (unchanged from previous round — see attn_fused for this round's changes)
template <int MODE, int BN>
__global__ __launch_bounds__(256, 4)
void gemm_bt(const u16* __restrict__ A, const u16* __restrict__ Bt,
             const float* __restrict__ bias, void* __restrict__ Cout,
             u16* __restrict__ Vt, int M, int N, int K) {
  __shared__ u16 As[2][128 * 32];
  __shared__ u16 Bs[2][BN * 32];
  constexpr int JT = BN / 32;          // j-tiles per wave
  const int tid = threadIdx.x;
  const int ln  = tid & 63;
  const int w   = tid >> 6;
  const int wm  = w >> 1, wn = w & 1;
  const int l15 = ln & 15, lq = ln >> 4;
  const int swz2 = (l15 >> 1) & 3;
  const int m0 = blockIdx.y * 128, n0 = blockIdx.x * BN;

  int aoff[2], boff[BN / 128 + 1];
  #pragma unroll
  for (int i = 0; i < 2; ++i) {
    int s = i * 256 + tid;                 // A: 512 slots
    int row = s >> 2, cg = (s & 3) ^ ((s >> 3) & 3);
    aoff[i] = (m0 + row) * K + cg * 8;
  }
  #pragma unroll
  for (int i = 0; i < BN / 128 + 1; ++i) { // B: BN*4 slots (512 or 256)
    int s = i * 256 + tid;
    int row = s >> 2, cg = (s & 3) ^ ((s >> 3) & 3);
    boff[i] = (n0 + row) * K + cg * 8;
  }

  f32x4 acc[4][JT];
  #pragma unroll
  for (int i = 0; i < 4; ++i)
    #pragma unroll
    for (int j = 0; j < JT; ++j)
      acc[i][j] = (f32x4){0.f, 0.f, 0.f, 0.f};

  const int NK = K >> 5;
  #pragma unroll
  for (int i = 0; i < 2; ++i)
    gl2lds16(A + aoff[i], (char*)As[0] + (size_t)(i * 256 + w * 64) * 16);
  #pragma unroll
  for (int i = 0; i < BN / 128 + 1; ++i)
    gl2lds16(Bt + boff[i], (char*)Bs[0] + (size_t)(i * 256 + w * 64) * 16);

  for (int it = 0; it < NK; ++it) {
    const int p = it & 1;
    __syncthreads();   // tile `it` landed (vmcnt drained); buf p^1 readers done
    if (it + 1 < NK) {
      const int k0 = (it + 1) * 32;
      #pragma unroll
      for (int i = 0; i < 2; ++i)
        gl2lds16(A + aoff[i] + k0, (char*)As[p ^ 1] + (size_t)(i * 256 + w * 64) * 16);
      #pragma unroll
      for (int i = 0; i < BN / 128 + 1; ++i)
        gl2lds16(Bt + boff[i] + k0, (char*)Bs[p ^ 1] + (size_t)(i * 256 + w * 64) * 16);
    }
    const u16* AsB = As[p];
    const u16* BsB = Bs[p];
    bf16x8 af[4], bfr[JT];
    #pragma unroll
    for (int i = 0; i < 4; ++i)
      af[i] = ldb8(&AsB[(wm * 64 + i * 16 + l15) * 32 + ((lq ^ swz2) * 8)]);
    #pragma unroll
    for (int j = 0; j < JT; ++j)
      bfr[j] = ldb8(&BsB[(wn * (BN / 2) + j * 16 + l15) * 32 + ((lq ^ swz2) * 8)]);
    #pragma unroll
    for (int i = 0; i < 4; ++i)
      #pragma unroll
      for (int j = 0; j < JT; ++j)
        acc[i][j] = __builtin_amdgcn_mfma_f32_16x16x32_bf16(af[i], bfr[j], acc[i][j], 0, 0, 0);
  }

  if (MODE == 1 && n0 >= 2048) {
    #pragma unroll
    for (int i = 0; i < 4; ++i) {
      int rowb = m0 + wm * 64 + i * 16 + lq * 4;   // 4 consecutive t
      int b_ = rowb >> 11, t0 = rowb & 2047;
      int tl = t0 & 63;
      int c = tl >> 4, ll = (tl >> 2) & 3;
      int pos0 = (c >> 1) * 32 + ll * 8 + (c & 1) * 4;
      size_t tdst = (size_t)(t0 & ~63) + pos0;
      #pragma unroll
      for (int j = 0; j < JT; ++j) {
        int col = n0 + wn * (BN / 2) + j * 16 + l15;
        int hd = col - 2048;
        float bsv = bias[col];
        u16x4 pk;
        #pragma unroll
        for (int r = 0; r < 4; ++r) pk[r] = f2bf(acc[i][j][r] + bsv);
        *(u16x4*)&Vt[(size_t)(b_ * 1024 + hd) * Tt + tdst] = pk;
      }
    }
  } else {
    const int ldc = (MODE == 1) ? 2048 : N;
    #pragma unroll
    for (int i = 0; i < 4; ++i) {
      int row = m0 + wm * 64 + i * 16 + lq * 4;
      #pragma unroll
      for (int j = 0; j < JT; ++j) {
        int col = n0 + wn * (BN / 2) + j * 16 + l15;
        float bsv = bias[col];
        #pragma unroll
        for (int r = 0; r < 4; ++r) {
          float v = acc[i][j][r] + bsv;
          if (MODE == 1) ((u16*)Cout)[(size_t)(row + r) * ldc + col] = f2bf(v);
          else           ((float*)Cout)[(size_t)(row + r) * ldc + col] = v;
        }
      }
    }
  }
}

// ============ fused causal flash attention — fused q-tile pair, O^T ============
// Block = 256 thr = 4 waves. Each block owns TWO q-tiles (qtA=31-pr, qtB=pr)
// processed CONCURRENTLY in ONE kv loop (32-pr iters; tile B active while
// it <= pr). K/V staging AND the K/V LDS fragment reads are shared by both
// tiles -> same bytes feed up to 2x the MFMAs, and the two independent
// softmax chains interleave (intra-wave latency hiding, since occupancy is
// capped at ~2 blocks/CU and round-1 showed more waves don't help).
// Complementary pairing: blocks bx and bx+256 (same XCD/CU slot under
// round-robin dispatch) get pr=g and pr=15-g -> 49 iters per CU everywhere.
// Row-sum l is computed by an extra MFMA with an all-ones A-fragment
// (D[m][q] = sum_k P[k][q], layout-independent) -> the 15-op tree sum and its
// two cross-lane shuffle round-trips are gone from the serial chain; only the
// row-max still needs 2 cross-lane hops (xor16 via shfl, xor32 via
// permlane32_swap = pure VALU, no LDS round-trip).
// Defer-max (THR=8, log2 domain) skips the alpha-rescale on most iterations.

__device__ __forceinline__ bf16x8 packp(const f32x4& a, const f32x4& b) {
  bf16x8 r;
  #pragma unroll
  for (int i = 0; i < 4; ++i) { r[i] = (__bf16)a[i]; r[i + 4] = (__bf16)b[i]; }
  return r;
}
__device__ __forceinline__ bf16x8 qscale(const u16* p) {
  u16x8 q = *(const u16x8*)p;
  u16x8 s;
  #pragma unroll
  for (int j = 0; j < 8; ++j) s[j] = f2bf(bf2f(q[j]) * SCALE2);
  return __builtin_bit_cast(bf16x8, s);
}

// mask (diagonal only) + row-max + defer-max rescale + exp2; P left in t.
__device__ __forceinline__ void softmax_step(f32x4 (&t)[4], float& m, f32x4 (&o)[4],
                                             f32x4& lacc, bool maskDiag, int kk,
                                             int qg, int lq) {
  if (maskDiag) {
    #pragma unroll
    for (int i = 0; i < 4; ++i)
      #pragma unroll
      for (int r = 0; r < 4; ++r) {
        int kv = kk + i * 16 + lq * 4 + r;
        if (kv > qg) t[i][r] = -__builtin_inff();
      }
  }
  float a0 = fmaxf(fmaxf(t[0][0], t[0][1]), fmaxf(t[0][2], t[0][3]));
  float a1 = fmaxf(fmaxf(t[1][0], t[1][1]), fmaxf(t[1][2], t[1][3]));
  float a2 = fmaxf(fmaxf(t[2][0], t[2][1]), fmaxf(t[2][2], t[2][3]));
  float a3 = fmaxf(fmaxf(t[3][0], t[3][1]), fmaxf(t[3][2], t[3][3]));
  float mx = fmaxf(fmaxf(a0, a1), fmaxf(a2, a3));
  mx = fmaxf(mx, __shfl_xor(mx, 16));
#if __has_builtin(__builtin_amdgcn_permlane32_swap)
  {
    unsigned mu = __builtin_bit_cast(unsigned, mx);
    auto r2 = __builtin_amdgcn_permlane32_swap(mu, mu, false, false);
    mx = fmaxf(__builtin_bit_cast(float, (unsigned)r2[0]),
               __builtin_bit_cast(float, (unsigned)r2[1]));
  }
#else
  mx = fmaxf(mx, __shfl_xor(mx, 32));
#endif
  if (!__all(mx <= m + 8.0f)) {
    float mn = fmaxf(m, mx);
    float al = __builtin_amdgcn_exp2f(m - mn);
    m = mn;
    lacc[0] *= al;   // only row 0 of the l-accumulator is ever read
    #pragma unroll
    for (int jd = 0; jd < 4; ++jd)
      #pragma unroll
      for (int r = 0; r < 4; ++r) o[jd][r] *= al;
  }
  #pragma unroll
  for (int i = 0; i < 4; ++i)
    #pragma unroll
    for (int r = 0; r < 4; ++r)
      t[i][r] = __builtin_amdgcn_exp2f(t[i][r] - m);
}

__global__ __launch_bounds__(256, 2)
void attn_fused(const u16* __restrict__ qk, const u16* __restrict__ vt,
                u16* __restrict__ y) {
  __shared__ u16 Ks[2][64 * 64];    // swizzled [kv-row][d], double-buffered
  __shared__ u16 Vts[2][64 * 64];   // swizzled [d-row][kv-permuted]
  const int tid = threadIdx.x;
  const int ln = tid & 63, w = tid >> 6;
  const int l15 = ln & 15, lq = ln >> 4;
  const int swz = l15 & 7;
  const int bx = blockIdx.x;        // 0..511
  const int bh = bx & 31;
  const int h  = bh & 15, b = bh >> 4;
  const int g  = (bx >> 5) & 7;
  const int pr = (bx < 256) ? g : 15 - g;   // complementary pairing bx <-> bx+256
  const int qtA = 31 - pr, qtB = pr;

  const u16* qbase = qk + (size_t)(b * Tt) * 2048 + h * HD;
  const u16* kbase = qk + (size_t)(b * Tt) * 2048 + 1024 + h * HD;
  const u16* vbase = vt + (size_t)(b * 1024 + h * HD) * Tt;

  // staging: thread handles slots s0=tid, s1=256+tid; row=s>>3, swizzled chunk
  const int s0 = tid, s1 = 256 + tid;
  const int koff0 = (s0 >> 3) * 2048 + (((s0 & 7) ^ ((s0 >> 3) & 7)) * 8);
  const int koff1 = (s1 >> 3) * 2048 + (((s1 & 7) ^ ((s1 >> 3) & 7)) * 8);

  const int q0A = qtA * 64 + w * 16;
  const int q0B = qtB * 64 + w * 16;

  // Q B-fragments for both tiles (n=q=l15, k=d), prescaled by 1/sqrt(d)*log2e
  const u16* qrA = qbase + (size_t)(q0A + l15) * 2048;
  const u16* qrB = qbase + (size_t)(q0B + l15) * 2048;
  bf16x8 qA0 = qscale(qrA + lq * 8), qA1 = qscale(qrA + 32 + lq * 8);
  bf16x8 qB0 = qscale(qrB + lq * 8), qB1 = qscale(qrB + 32 + lq * 8);

  bf16x8 ones;
  #pragma unroll
  for (int j = 0; j < 8; ++j) ones[j] = (__bf16)1.0f;

  f32x4 oA[4], oB[4];
  #pragma unroll
  for (int j = 0; j < 4; ++j) { oA[j] = (f32x4){0, 0, 0, 0}; oB[j] = (f32x4){0, 0, 0, 0}; }
  f32x4 laccA = (f32x4){0, 0, 0, 0}, laccB = (f32x4){0, 0, 0, 0};
  float mA = -__builtin_inff(), mB = -__builtin_inff();
  const int qgA = q0A + l15, qgB = q0B + l15;

  const int itLast = qtA;   // kv tiles 0..31-pr

  // prologue: stage kv-tile 0 into buffer 0
  gl2lds16(kbase + koff0, (char*)Ks[0] + w * 1024);
  gl2lds16(kbase + koff1, (char*)Ks[0] + 4096 + w * 1024);
  gl2lds16(vbase + koff0, (char*)Vts[0] + w * 1024);
  gl2lds16(vbase + koff1, (char*)Vts[0] + 4096 + w * 1024);

  for (int it = 0; it <= itLast; ++it) {
    const int kk = it * 64;
    const int p = it & 1;
    __syncthreads();   // tile `it` staged (vmcnt drained); buf p^1 readers done
    if (it < itLast) {
      const u16* ksrc = kbase + (size_t)(kk + 64) * 2048;
      const u16* vsrc = vbase + kk + 64;
      gl2lds16(ksrc + koff0, (char*)Ks[p ^ 1] + w * 1024);
      gl2lds16(ksrc + koff1, (char*)Ks[p ^ 1] + 4096 + w * 1024);
      gl2lds16(vsrc + koff0, (char*)Vts[p ^ 1] + w * 1024);
      gl2lds16(vsrc + koff1, (char*)Vts[p ^ 1] + 4096 + w * 1024);
    }
    const u16* KsB  = Ks[p];
    const u16* VtsB = Vts[p];
    const bool actB = (it <= qtB);

    // S^T = K * Q^T for both tiles; K fragments shared
    f32x4 tA[4], tB[4];
    #pragma unroll
    for (int i = 0; i < 4; ++i) { tA[i] = (f32x4){0, 0, 0, 0}; tB[i] = (f32x4){0, 0, 0, 0}; }
    __builtin_amdgcn_s_setprio(1);
    #pragma unroll
    for (int i = 0; i < 4; ++i) {
      bf16x8 kf0 = ldb8(&KsB[(i * 16 + l15) * 64 + ((lq    ) ^ swz) * 8]);
      bf16x8 kf1 = ldb8(&KsB[(i * 16 + l15) * 64 + ((lq + 4) ^ swz) * 8]);
      tA[i] = __builtin_amdgcn_mfma_f32_16x16x32_bf16(kf0, qA0, tA[i], 0, 0, 0);
      tA[i] = __builtin_amdgcn_mfma_f32_16x16x32_bf16(kf1, qA1, tA[i], 0, 0, 0);
      if (actB) {
        tB[i] = __builtin_amdgcn_mfma_f32_16x16x32_bf16(kf0, qB0, tB[i], 0, 0, 0);
        tB[i] = __builtin_amdgcn_mfma_f32_16x16x32_bf16(kf1, qB1, tB[i], 0, 0, 0);
      }
    }
    __builtin_amdgcn_s_setprio(0);

    // two independent softmax chains (compiler interleaves them)
    softmax_step(tA, mA, oA, laccA, it == itLast, kk, qgA, lq);
    bf16x8 pA0 = packp(tA[0], tA[1]), pA1 = packp(tA[2], tA[3]);
    bf16x8 pB0 = {}, pB1 = {};
    if (actB) {
      softmax_step(tB, mB, oB, laccB, it == qtB, kk, qgB, lq);
      pB0 = packp(tB[0], tB[1]); pB1 = packp(tB[2], tB[3]);
    }

    // O^T += V^T * P ; l += ones * P (row-sum via MFMA). V fragments shared.
    __builtin_amdgcn_s_setprio(1);
    #pragma unroll
    for (int mf = 0; mf < 2; ++mf) {
      bf16x8 pa = mf ? pA1 : pA0;
      bf16x8 pb = mf ? pB1 : pB0;
      laccA = __builtin_amdgcn_mfma_f32_16x16x32_bf16(ones, pa, laccA, 0, 0, 0);
      if (actB)
        laccB = __builtin_amdgcn_mfma_f32_16x16x32_bf16(ones, pb, laccB, 0, 0, 0);
      #pragma unroll
      for (int jd = 0; jd < 4; ++jd) {
        int d = jd * 16 + l15;
        bf16x8 vf = ldb8(&VtsB[d * 64 + ((mf * 4 + lq) ^ swz) * 8]);
        oA[jd] = __builtin_amdgcn_mfma_f32_16x16x32_bf16(vf, pa, oA[jd], 0, 0, 0);
        if (actB)
          oB[jd] = __builtin_amdgcn_mfma_f32_16x16x32_bf16(vf, pb, oB[jd], 0, 0, 0);
      }
    }
    __builtin_amdgcn_s_setprio(0);
  }

  // epilogue: per-lane normalize, store O^T[d][q] -> y[q][d] as u16x4 runs
  {
    float inv = 1.f / laccA[0];
    const size_t ybase = (size_t)(b * Tt + q0A + l15) * Cc + h * HD;
    #pragma unroll
    for (int jd = 0; jd < 4; ++jd) {
      u16x4 pk;
      #pragma unroll
      for (int r = 0; r < 4; ++r) pk[r] = f2bf(oA[jd][r] * inv);
      *(u16x4*)&y[ybase + jd * 16 + lq * 4] = pk;
    }
  }
  {
    float inv = 1.f / laccB[0];
    const size_t ybase = (size_t)(b * Tt + q0B + l15) * Cc + h * HD;
    #pragma unroll
    for (int jd = 0; jd < 4; ++jd) {
      u16x4 pk;
      #pragma unroll
      for (int r = 0; r < 4; ++r) pk[r] = f2bf(oB[jd][r] * inv);
      *(u16x4*)&y[ybase + jd * 16 + lq * 4] = pk;
    }
  }
}

extern "C" void kernel_launch(void* const* d_in, const int* in_sizes, int n_in,
                              void* d_out, int out_size, void* d_ws, size_t ws_size,
                              hipStream_t stream) {
  const float* x      = (const float*)d_in[0];
  const float* w_attn = (const float*)d_in[1];
  const float* b_attn = (const float*)d_in[2];
  const float* w_proj = (const float*)d_in[3];
  const float* b_proj = (const float*)d_in[4];
  float* out = (float*)d_out;

  char* ws = (char*)d_ws;
  u16* xb  = (u16*)(ws + 0);          // 4096x1024 bf16   (8 MB)
  u16* wat = (u16*)(ws + 8388608);    // 3072x1024 bf16   (6 MB)   w_attn^T
  u16* wpt = (u16*)(ws + 14680064);   // 1024x1024 bf16   (2 MB)   w_proj^T
  u16* qkb = (u16*)(ws + 16777216);   // 4096x2048 bf16   (16 MB)  Q,K
  u16* vtb = (u16*)(ws + 33554432);   // 2048x2048 bf16   (8 MB)   V^T (permuted)
  u16* yb  = (u16*)(ws + 41943040);   // 4096x1024 bf16   (8 MB)

  prep_kernel<<<5120, 256, 0, stream>>>(x, w_attn, w_proj, xb, wat, wpt);
  gemm_bt<1, 128><<<dim3(24, 32), 256, 0, stream>>>(xb, wat, b_attn, (void*)qkb, vtb, 4096, 3072, 1024);
  attn_fused<<<512, 256, 0, stream>>>(qkb, vtb, yb);
  gemm_bt<0, 64><<<dim3(16, 32), 256, 0, stream>>>(yb, wpt, b_proj, (void*)out, nullptr, 4096, 1024, 1024);
}

// Round 3
// 182.721 us; speedup vs baseline: 1.0216x; 1.0216x over previous
//
#include <hip/hip_runtime.h>
#include <stdint.h>

#define Bb 2
#define Tt 2048
#define Cc 1024
#define Hh 16
#define HD 64
#define C3 3072

typedef __bf16 bf16x8 __attribute__((ext_vector_type(8)));
typedef float  f32x4  __attribute__((ext_vector_type(4)));
typedef unsigned short u16;
typedef u16 u16x8 __attribute__((ext_vector_type(8)));
typedef u16 u16x4 __attribute__((ext_vector_type(4)));

#define SCALE2 0.18033688f  /* 1/sqrt(64) * log2(e) */

__device__ __forceinline__ u16 f2bf(float f) {
  union { float f; unsigned u; } v; v.f = f;
  return (u16)((v.u + 0x7fffu + ((v.u >> 16) & 1u)) >> 16);  // RNE
}
__device__ __forceinline__ float bf2f(u16 a) {
  union { unsigned u; float f; } v; v.u = ((unsigned)a) << 16; return v.f;
}

// async global->LDS, 16B per lane. LDS dest = wave-uniform base + lane*16.
__device__ __forceinline__ void gl2lds16(const void* g, void* s) {
  __builtin_amdgcn_global_load_lds(
      (__attribute__((address_space(1))) void*)(g),
      (__attribute__((address_space(3))) void*)(s), 16, 0, 0);
}

__device__ __forceinline__ bf16x8 ldb8(const u16* p) {
  return __builtin_bit_cast(bf16x8, *(const u16x8*)p);
}

// ---------------- merged prep: cvt_x + w_attn^T + w_proj^T ----------------
__global__ __launch_bounds__(256)
void prep_kernel(const float* __restrict__ x, const float* __restrict__ w_attn,
                 const float* __restrict__ w_proj, u16* __restrict__ xb,
                 u16* __restrict__ wat, u16* __restrict__ wpt) {
  __shared__ u16 tile[64][65];
  const int blk = blockIdx.x;
  const int tid = threadIdx.x;
  if (blk < 4096) {
    int i = blk * 256 + tid;
    float4 v = ((const float4*)x)[i];
    u16x4 o = { f2bf(v.x), f2bf(v.y), f2bf(v.z), f2bf(v.w) };
    ((u16x4*)xb)[i] = o;
    return;
  }
  const float* in; u16* out; int R, C, c0, r0;
  if (blk < 4096 + 768) {
    int t = blk - 4096;
    in = w_attn; out = wat; R = 1024; C = 3072;
    c0 = (t % 48) * 64; r0 = (t / 48) * 64;
  } else {
    int t = blk - 4864;
    in = w_proj; out = wpt; R = 1024; C = 1024;
    c0 = (t & 15) * 64; r0 = (t >> 4) * 64;
  }
  int xx = tid & 63, yy = tid >> 6;
  #pragma unroll
  for (int rr = yy; rr < 64; rr += 4)
    tile[rr][xx] = f2bf(in[(size_t)(r0 + rr) * C + c0 + xx]);
  __syncthreads();
  #pragma unroll
  for (int rr = yy; rr < 64; rr += 4)
    out[(size_t)(c0 + rr) * R + r0 + xx] = tile[xx][rr];
}

// ---------------- bf16 GEMM: C[M][N] = A[M][K] * Bt[N][K]^T + bias ----------------
// (unchanged — this round's changes are in attn_fused)
template <int MODE, int BN>
__global__ __launch_bounds__(256, 4)
void gemm_bt(const u16* __restrict__ A, const u16* __restrict__ Bt,
             const float* __restrict__ bias, void* __restrict__ Cout,
             u16* __restrict__ Vt, int M, int N, int K) {
  __shared__ u16 As[2][128 * 32];
  __shared__ u16 Bs[2][BN * 32];
  constexpr int JT = BN / 32;          // j-tiles per wave
  const int tid = threadIdx.x;
  const int ln  = tid & 63;
  const int w   = tid >> 6;
  const int wm  = w >> 1, wn = w & 1;
  const int l15 = ln & 15, lq = ln >> 4;
  const int swz2 = (l15 >> 1) & 3;
  const int m0 = blockIdx.y * 128, n0 = blockIdx.x * BN;

  int aoff[2], boff[BN / 128 + 1];
  #pragma unroll
  for (int i = 0; i < 2; ++i) {
    int s = i * 256 + tid;                 // A: 512 slots
    int row = s >> 2, cg = (s & 3) ^ ((s >> 3) & 3);
    aoff[i] = (m0 + row) * K + cg * 8;
  }
  #pragma unroll
  for (int i = 0; i < BN / 128 + 1; ++i) { // B: BN*4 slots (512 or 256)
    int s = i * 256 + tid;
    int row = s >> 2, cg = (s & 3) ^ ((s >> 3) & 3);
    boff[i] = (n0 + row) * K + cg * 8;
  }

  f32x4 acc[4][JT];
  #pragma unroll
  for (int i = 0; i < 4; ++i)
    #pragma unroll
    for (int j = 0; j < JT; ++j)
      acc[i][j] = (f32x4){0.f, 0.f, 0.f, 0.f};

  const int NK = K >> 5;
  #pragma unroll
  for (int i = 0; i < 2; ++i)
    gl2lds16(A + aoff[i], (char*)As[0] + (size_t)(i * 256 + w * 64) * 16);
  #pragma unroll
  for (int i = 0; i < BN / 128 + 1; ++i)
    gl2lds16(Bt + boff[i], (char*)Bs[0] + (size_t)(i * 256 + w * 64) * 16);

  for (int it = 0; it < NK; ++it) {
    const int p = it & 1;
    __syncthreads();   // tile `it` landed (vmcnt drained); buf p^1 readers done
    if (it + 1 < NK) {
      const int k0 = (it + 1) * 32;
      #pragma unroll
      for (int i = 0; i < 2; ++i)
        gl2lds16(A + aoff[i] + k0, (char*)As[p ^ 1] + (size_t)(i * 256 + w * 64) * 16);
      #pragma unroll
      for (int i = 0; i < BN / 128 + 1; ++i)
        gl2lds16(Bt + boff[i] + k0, (char*)Bs[p ^ 1] + (size_t)(i * 256 + w * 64) * 16);
    }
    const u16* AsB = As[p];
    const u16* BsB = Bs[p];
    bf16x8 af[4], bfr[JT];
    #pragma unroll
    for (int i = 0; i < 4; ++i)
      af[i] = ldb8(&AsB[(wm * 64 + i * 16 + l15) * 32 + ((lq ^ swz2) * 8)]);
    #pragma unroll
    for (int j = 0; j < JT; ++j)
      bfr[j] = ldb8(&BsB[(wn * (BN / 2) + j * 16 + l15) * 32 + ((lq ^ swz2) * 8)]);
    #pragma unroll
    for (int i = 0; i < 4; ++i)
      #pragma unroll
      for (int j = 0; j < JT; ++j)
        acc[i][j] = __builtin_amdgcn_mfma_f32_16x16x32_bf16(af[i], bfr[j], acc[i][j], 0, 0, 0);
  }

  if (MODE == 1 && n0 >= 2048) {
    #pragma unroll
    for (int i = 0; i < 4; ++i) {
      int rowb = m0 + wm * 64 + i * 16 + lq * 4;   // 4 consecutive t
      int b_ = rowb >> 11, t0 = rowb & 2047;
      int tl = t0 & 63;
      int c = tl >> 4, ll = (tl >> 2) & 3;
      int pos0 = (c >> 1) * 32 + ll * 8 + (c & 1) * 4;
      size_t tdst = (size_t)(t0 & ~63) + pos0;
      #pragma unroll
      for (int j = 0; j < JT; ++j) {
        int col = n0 + wn * (BN / 2) + j * 16 + l15;
        int hd = col - 2048;
        float bsv = bias[col];
        u16x4 pk;
        #pragma unroll
        for (int r = 0; r < 4; ++r) pk[r] = f2bf(acc[i][j][r] + bsv);
        *(u16x4*)&Vt[(size_t)(b_ * 1024 + hd) * Tt + tdst] = pk;
      }
    }
  } else {
    const int ldc = (MODE == 1) ? 2048 : N;
    #pragma unroll
    for (int i = 0; i < 4; ++i) {
      int row = m0 + wm * 64 + i * 16 + lq * 4;
      #pragma unroll
      for (int j = 0; j < JT; ++j) {
        int col = n0 + wn * (BN / 2) + j * 16 + l15;
        float bsv = bias[col];
        #pragma unroll
        for (int r = 0; r < 4; ++r) {
          float v = acc[i][j][r] + bsv;
          if (MODE == 1) ((u16*)Cout)[(size_t)(row + r) * ldc + col] = f2bf(v);
          else           ((float*)Cout)[(size_t)(row + r) * ldc + col] = v;
        }
      }
    }
  }
}

// ============ fused causal flash attention — 128-q block, O^T ============
// LDS-read-BW is the measured bottleneck (R0-R2 post-mortem: 80KB LDS traffic
// per block-iter at ~90B/cy/CU fits the 3400cy/iter plateau; K/V fragment
// addresses are wave-index-independent, so 4 waves re-read identical bytes).
// Fix: each wave covers 32 q rows as TWO always-active 16-row subtiles
// (lo = q0+w*16, hi = q0+64+w*16); block covers a 128-row q-block. The same
// K/V fragment reads now feed 2x the q-work -> LDS read bytes per unit work
// halved; per-CU traffic 5.3MB -> 2.9MB. Unlike round-2's heavy/light pair,
// both subtiles are adjacent, so lo is active for EVERY kv tile except the
// single final one -> sharing ~100% effective on all blocks. Two independent
// softmax chains per wave keep 4 chains/SIMD (= R0 concurrency) at 2 blocks/CU.
// Grid: 16 q-blocks x 32 bh = 512 blocks; complementary pairing (bx <-> bx+256
// get qb = g and 15-g) -> uniform 36 block-iters per CU.
// Micro: tree-max, permlane32_swap max hop, defer-max (THR=8 log2), row-sum l
// via MFMA ones-trick (no cross-lane sum), native cvt-pack, setprio on MFMA.

__device__ __forceinline__ bf16x8 packp(const f32x4& a, const f32x4& b) {
  bf16x8 r;
  #pragma unroll
  for (int i = 0; i < 4; ++i) { r[i] = (__bf16)a[i]; r[i + 4] = (__bf16)b[i]; }
  return r;
}
__device__ __forceinline__ bf16x8 qscale(const u16* p) {
  u16x8 q = *(const u16x8*)p;
  u16x8 s;
  #pragma unroll
  for (int j = 0; j < 8; ++j) s[j] = f2bf(bf2f(q[j]) * SCALE2);
  return __builtin_bit_cast(bf16x8, s);
}

// mask (diagonal only) + row-max + defer-max rescale + exp2; P left in t.
__device__ __forceinline__ void softmax_step(f32x4 (&t)[4], float& m, f32x4 (&o)[4],
                                             f32x4& lacc, bool maskDiag, int kk,
                                             int qg, int lq) {
  if (maskDiag) {
    #pragma unroll
    for (int i = 0; i < 4; ++i)
      #pragma unroll
      for (int r = 0; r < 4; ++r) {
        int kv = kk + i * 16 + lq * 4 + r;
        if (kv > qg) t[i][r] = -__builtin_inff();
      }
  }
  float a0 = fmaxf(fmaxf(t[0][0], t[0][1]), fmaxf(t[0][2], t[0][3]));
  float a1 = fmaxf(fmaxf(t[1][0], t[1][1]), fmaxf(t[1][2], t[1][3]));
  float a2 = fmaxf(fmaxf(t[2][0], t[2][1]), fmaxf(t[2][2], t[2][3]));
  float a3 = fmaxf(fmaxf(t[3][0], t[3][1]), fmaxf(t[3][2], t[3][3]));
  float mx = fmaxf(fmaxf(a0, a1), fmaxf(a2, a3));
  mx = fmaxf(mx, __shfl_xor(mx, 16));
#if __has_builtin(__builtin_amdgcn_permlane32_swap)
  {
    unsigned mu = __builtin_bit_cast(unsigned, mx);
    auto r2 = __builtin_amdgcn_permlane32_swap(mu, mu, false, false);
    mx = fmaxf(__builtin_bit_cast(float, (unsigned)r2[0]),
               __builtin_bit_cast(float, (unsigned)r2[1]));
  }
#else
  mx = fmaxf(mx, __shfl_xor(mx, 32));
#endif
  if (!__all(mx <= m + 8.0f)) {
    float mn = fmaxf(m, mx);
    float al = __builtin_amdgcn_exp2f(m - mn);
    m = mn;
    lacc[0] *= al;   // only element 0 of the l-accumulator is ever read
    #pragma unroll
    for (int jd = 0; jd < 4; ++jd)
      #pragma unroll
      for (int r = 0; r < 4; ++r) o[jd][r] *= al;
  }
  #pragma unroll
  for (int i = 0; i < 4; ++i)
    #pragma unroll
    for (int r = 0; r < 4; ++r)
      t[i][r] = __builtin_amdgcn_exp2f(t[i][r] - m);
}

__global__ __launch_bounds__(256, 2)
void attn_fused(const u16* __restrict__ qk, const u16* __restrict__ vt,
                u16* __restrict__ y) {
  __shared__ u16 Ks[2][64 * 64];    // swizzled [kv-row][d], double-buffered
  __shared__ u16 Vts[2][64 * 64];   // swizzled [d-row][kv-permuted]
  const int tid = threadIdx.x;
  const int ln = tid & 63, w = tid >> 6;
  const int l15 = ln & 15, lq = ln >> 4;
  const int swz = l15 & 7;
  const int bx = blockIdx.x;        // 0..511
  const int bh = bx & 31;
  const int h  = bh & 15, b = bh >> 4;
  const int g  = (bx >> 5) & 7;
  const int qb = (bx < 256) ? g : 15 - g;  // complementary pairing bx <-> bx+256
  const int q0 = qb * 128;

  const u16* qbase = qk + (size_t)(b * Tt) * 2048 + h * HD;
  const u16* kbase = qk + (size_t)(b * Tt) * 2048 + 1024 + h * HD;
  const u16* vbase = vt + (size_t)(b * 1024 + h * HD) * Tt;

  // staging: thread handles slots s0=tid, s1=256+tid; row=s>>3, swizzled chunk
  const int s0 = tid, s1 = 256 + tid;
  const int koff0 = (s0 >> 3) * 2048 + (((s0 & 7) ^ ((s0 >> 3) & 7)) * 8);
  const int koff1 = (s1 >> 3) * 2048 + (((s1 & 7) ^ ((s1 >> 3) & 7)) * 8);

  const int rLo = q0 + w * 16;        // lo subtile base row
  const int rHi = q0 + 64 + w * 16;   // hi subtile base row

  // Q B-fragments for both subtiles (n=q=l15, k=d), prescaled by 1/sqrt(d)*log2e
  const u16* qrL = qbase + (size_t)(rLo + l15) * 2048;
  const u16* qrH = qbase + (size_t)(rHi + l15) * 2048;
  bf16x8 qL0 = qscale(qrL + lq * 8), qL1 = qscale(qrL + 32 + lq * 8);
  bf16x8 qH0 = qscale(qrH + lq * 8), qH1 = qscale(qrH + 32 + lq * 8);

  bf16x8 ones;
  #pragma unroll
  for (int j = 0; j < 8; ++j) ones[j] = (__bf16)1.0f;

  f32x4 oL[4], oH[4];
  #pragma unroll
  for (int j = 0; j < 4; ++j) { oL[j] = (f32x4){0, 0, 0, 0}; oH[j] = (f32x4){0, 0, 0, 0}; }
  f32x4 laccL = (f32x4){0, 0, 0, 0}, laccH = (f32x4){0, 0, 0, 0};
  float mL = -__builtin_inff(), mH = -__builtin_inff();
  const int qgL = rLo + l15, qgH = rHi + l15;
  const int diagLo = 2 * qb;          // lo's diagonal kv tile
  const int itLast = 2 * qb + 1;      // hi's diagonal kv tile (= last iter)

  // prologue: stage kv-tile 0 into buffer 0
  gl2lds16(kbase + koff0, (char*)Ks[0] + w * 1024);
  gl2lds16(kbase + koff1, (char*)Ks[0] + 4096 + w * 1024);
  gl2lds16(vbase + koff0, (char*)Vts[0] + w * 1024);
  gl2lds16(vbase + koff1, (char*)Vts[0] + 4096 + w * 1024);

  for (int it = 0; it <= itLast; ++it) {
    const int kk = it * 64;
    const int p = it & 1;
    __syncthreads();   // tile `it` staged (vmcnt drained); buf p^1 readers done
    if (it < itLast) {
      const u16* ksrc = kbase + (size_t)(kk + 64) * 2048;
      const u16* vsrc = vbase + kk + 64;
      gl2lds16(ksrc + koff0, (char*)Ks[p ^ 1] + w * 1024);
      gl2lds16(ksrc + koff1, (char*)Ks[p ^ 1] + 4096 + w * 1024);
      gl2lds16(vsrc + koff0, (char*)Vts[p ^ 1] + w * 1024);
      gl2lds16(vsrc + koff1, (char*)Vts[p ^ 1] + 4096 + w * 1024);
    }
    const u16* KsB  = Ks[p];
    const u16* VtsB = Vts[p];
    const bool actLo = (it <= diagLo);   // lo inactive only on the final iter

    // S^T = K * Q^T for both subtiles; K fragments read once, used by both
    f32x4 tL[4], tH[4];
    #pragma unroll
    for (int i = 0; i < 4; ++i) { tL[i] = (f32x4){0, 0, 0, 0}; tH[i] = (f32x4){0, 0, 0, 0}; }
    __builtin_amdgcn_s_setprio(1);
    #pragma unroll
    for (int i = 0; i < 4; ++i) {
      bf16x8 kf0 = ldb8(&KsB[(i * 16 + l15) * 64 + ((lq    ) ^ swz) * 8]);
      bf16x8 kf1 = ldb8(&KsB[(i * 16 + l15) * 64 + ((lq + 4) ^ swz) * 8]);
      tH[i] = __builtin_amdgcn_mfma_f32_16x16x32_bf16(kf0, qH0, tH[i], 0, 0, 0);
      tH[i] = __builtin_amdgcn_mfma_f32_16x16x32_bf16(kf1, qH1, tH[i], 0, 0, 0);
      if (actLo) {
        tL[i] = __builtin_amdgcn_mfma_f32_16x16x32_bf16(kf0, qL0, tL[i], 0, 0, 0);
        tL[i] = __builtin_amdgcn_mfma_f32_16x16x32_bf16(kf1, qL1, tL[i], 0, 0, 0);
      }
    }
    __builtin_amdgcn_s_setprio(0);

    // two independent softmax chains (compiler interleaves them)
    bf16x8 pL0 = {}, pL1 = {};
    if (actLo) {
      softmax_step(tL, mL, oL, laccL, it == diagLo, kk, qgL, lq);
      pL0 = packp(tL[0], tL[1]); pL1 = packp(tL[2], tL[3]);
    }
    softmax_step(tH, mH, oH, laccH, it == itLast, kk, qgH, lq);
    bf16x8 pH0 = packp(tH[0], tH[1]), pH1 = packp(tH[2], tH[3]);

    // O^T += V^T * P ; l += ones * P (row-sum via MFMA). V fragments shared.
    __builtin_amdgcn_s_setprio(1);
    #pragma unroll
    for (int mf = 0; mf < 2; ++mf) {
      bf16x8 ph = mf ? pH1 : pH0;
      bf16x8 pl = mf ? pL1 : pL0;
      laccH = __builtin_amdgcn_mfma_f32_16x16x32_bf16(ones, ph, laccH, 0, 0, 0);
      if (actLo)
        laccL = __builtin_amdgcn_mfma_f32_16x16x32_bf16(ones, pl, laccL, 0, 0, 0);
      #pragma unroll
      for (int jd = 0; jd < 4; ++jd) {
        int d = jd * 16 + l15;
        bf16x8 vf = ldb8(&VtsB[d * 64 + ((mf * 4 + lq) ^ swz) * 8]);
        oH[jd] = __builtin_amdgcn_mfma_f32_16x16x32_bf16(vf, ph, oH[jd], 0, 0, 0);
        if (actLo)
          oL[jd] = __builtin_amdgcn_mfma_f32_16x16x32_bf16(vf, pl, oL[jd], 0, 0, 0);
      }
    }
    __builtin_amdgcn_s_setprio(0);
  }

  // epilogue: per-lane normalize, store O^T[d][q] -> y[q][d] as u16x4 runs
  {
    float inv = 1.f / laccL[0];
    const size_t ybase = (size_t)(b * Tt + rLo + l15) * Cc + h * HD;
    #pragma unroll
    for (int jd = 0; jd < 4; ++jd) {
      u16x4 pk;
      #pragma unroll
      for (int r = 0; r < 4; ++r) pk[r] = f2bf(oL[jd][r] * inv);
      *(u16x4*)&y[ybase + jd * 16 + lq * 4] = pk;
    }
  }
  {
    float inv = 1.f / laccH[0];
    const size_t ybase = (size_t)(b * Tt + rHi + l15) * Cc + h * HD;
    #pragma unroll
    for (int jd = 0; jd < 4; ++jd) {
      u16x4 pk;
      #pragma unroll
      for (int r = 0; r < 4; ++r) pk[r] = f2bf(oH[jd][r] * inv);
      *(u16x4*)&y[ybase + jd * 16 + lq * 4] = pk;
    }
  }
}

extern "C" void kernel_launch(void* const* d_in, const int* in_sizes, int n_in,
                              void* d_out, int out_size, void* d_ws, size_t ws_size,
                              hipStream_t stream) {
  const float* x      = (const float*)d_in[0];
  const float* w_attn = (const float*)d_in[1];
  const float* b_attn = (const float*)d_in[2];
  const float* w_proj = (const float*)d_in[3];
  const float* b_proj = (const float*)d_in[4];
  float* out = (float*)d_out;

  char* ws = (char*)d_ws;
  u16* xb  = (u16*)(ws + 0);          // 4096x1024 bf16   (8 MB)
  u16* wat = (u16*)(ws + 8388608);    // 3072x1024 bf16   (6 MB)   w_attn^T
  u16* wpt = (u16*)(ws + 14680064);   // 1024x1024 bf16   (2 MB)   w_proj^T
  u16* qkb = (u16*)(ws + 16777216);   // 4096x2048 bf16   (16 MB)  Q,K
  u16* vtb = (u16*)(ws + 33554432);   // 2048x2048 bf16   (8 MB)   V^T (permuted)
  u16* yb  = (u16*)(ws + 41943040);   // 4096x1024 bf16   (8 MB)

  prep_kernel<<<5120, 256, 0, stream>>>(x, w_attn, w_proj, xb, wat, wpt);
  gemm_bt<1, 128><<<dim3(24, 32), 256, 0, stream>>>(xb, wat, b_attn, (void*)qkb, vtb, 4096, 3072, 1024);
  attn_fused<<<512, 256, 0, stream>>>(qkb, vtb, yb);
  gemm_bt<0, 64><<<dim3(16, 32), 256, 0, stream>>>(yb, wpt, b_proj, (void*)out, nullptr, 4096, 1024, 1024);
}

// Round 4
// 174.471 us; speedup vs baseline: 1.0699x; 1.0473x over previous
//
#include <hip/hip_runtime.h>
#include <stdint.h>

#define Bb 2
#define Tt 2048
#define Cc 1024
#define Hh 16
#define HD 64
#define C3 3072

typedef __bf16 bf16x8 __attribute__((ext_vector_type(8)));
typedef float  f32x4  __attribute__((ext_vector_type(4)));
typedef unsigned short u16;
typedef u16 u16x8 __attribute__((ext_vector_type(8)));
typedef u16 u16x4 __attribute__((ext_vector_type(4)));

#define SCALE2 0.18033688f  /* 1/sqrt(64) * log2(e) */

__device__ __forceinline__ u16 f2bf(float f) {
  union { float f; unsigned u; } v; v.f = f;
  return (u16)((v.u + 0x7fffu + ((v.u >> 16) & 1u)) >> 16);  // RNE
}
__device__ __forceinline__ float bf2f(u16 a) {
  union { unsigned u; float f; } v; v.u = ((unsigned)a) << 16; return v.f;
}

// async global->LDS, 16B per lane. LDS dest = wave-uniform base + lane*16.
__device__ __forceinline__ void gl2lds16(const void* g, void* s) {
  __builtin_amdgcn_global_load_lds(
      (__attribute__((address_space(1))) void*)(g),
      (__attribute__((address_space(3))) void*)(s), 16, 0, 0);
}

__device__ __forceinline__ bf16x8 ldb8(const u16* p) {
  return __builtin_bit_cast(bf16x8, *(const u16x8*)p);
}

// counted vmcnt wait: allow N of this wave's VMEM ops to stay in flight.
template <int N>
__device__ __forceinline__ void vmwait() {
  asm volatile("s_waitcnt vmcnt(%0)" :: "n"(N) : "memory");
}
// barrier WITHOUT the compiler's vmcnt(0) drain (raw s_barrier); sched_barrier
// pins ds_reads below it (rule: lgkm ops must not hoist above the barrier).
__device__ __forceinline__ void barrier_nodrain() {
  __builtin_amdgcn_s_barrier();
  __builtin_amdgcn_sched_barrier(0);
}

// ---------------- merged prep: cvt_x + w_attn^T + w_proj^T ----------------
__global__ __launch_bounds__(256)
void prep_kernel(const float* __restrict__ x, const float* __restrict__ w_attn,
                 const float* __restrict__ w_proj, u16* __restrict__ xb,
                 u16* __restrict__ wat, u16* __restrict__ wpt) {
  __shared__ u16 tile[64][65];
  const int blk = blockIdx.x;
  const int tid = threadIdx.x;
  if (blk < 4096) {
    int i = blk * 256 + tid;
    float4 v = ((const float4*)x)[i];
    u16x4 o = { f2bf(v.x), f2bf(v.y), f2bf(v.z), f2bf(v.w) };
    ((u16x4*)xb)[i] = o;
    return;
  }
  const float* in; u16* out; int R, C, c0, r0;
  if (blk < 4096 + 768) {
    int t = blk - 4096;
    in = w_attn; out = wat; R = 1024; C = 3072;
    c0 = (t % 48) * 64; r0 = (t / 48) * 64;
  } else {
    int t = blk - 4864;
    in = w_proj; out = wpt; R = 1024; C = 1024;
    c0 = (t & 15) * 64; r0 = (t >> 4) * 64;
  }
  int xx = tid & 63, yy = tid >> 6;
  #pragma unroll
  for (int rr = yy; rr < 64; rr += 4)
    tile[rr][xx] = f2bf(in[(size_t)(r0 + rr) * C + c0 + xx]);
  __syncthreads();
  #pragma unroll
  for (int rr = yy; rr < 64; rr += 4)
    out[(size_t)(c0 + rr) * R + r0 + xx] = tile[xx][rr];
}

// ---------------- bf16 GEMM: C[M][N] = A[M][K] * Bt[N][K]^T + bias ----------------
// 128xBN tile, BK=32. TRIPLE-buffered LDS, depth-2 prefetch, counted-vmcnt
// barriers (T4): per iter each wave waits vmcnt(L) -- draining only the
// 2-iteration-old tile's loads while the newest tile's L loads stay in flight
// ACROSS the raw s_barrier (no compiler vmcnt(0) drain). Each staged load now
// has ~2 iterations of compute to land instead of <1. WAR on buf (it+2)%3 is
// protected by the iter-it barrier (its readers ran in iter it-1).
// 4-chunk XOR swizzle unchanged. MODE semantics unchanged.
template <int MODE, int BN, int MINW>
__global__ __launch_bounds__(256, MINW)
void gemm_bt(const u16* __restrict__ A, const u16* __restrict__ Bt,
             const float* __restrict__ bias, void* __restrict__ Cout,
             u16* __restrict__ Vt, int M, int N, int K) {
  __shared__ u16 As[3][128 * 32];
  __shared__ u16 Bs[3][BN * 32];
  constexpr int JT = BN / 32;          // j-tiles per wave
  constexpr int NB = BN / 128 + 1;     // B staging instrs per thread
  constexpr int L  = 2 + NB;           // loads in flight per thread per tile
  const int tid = threadIdx.x;
  const int ln  = tid & 63;
  const int w   = tid >> 6;
  const int wm  = w >> 1, wn = w & 1;
  const int l15 = ln & 15, lq = ln >> 4;
  const int swz2 = (l15 >> 1) & 3;
  const int m0 = blockIdx.y * 128, n0 = blockIdx.x * BN;

  int aoff[2], boff[NB];
  #pragma unroll
  for (int i = 0; i < 2; ++i) {
    int s = i * 256 + tid;                 // A: 512 slots
    int row = s >> 2, cg = (s & 3) ^ ((s >> 3) & 3);
    aoff[i] = (m0 + row) * K + cg * 8;
  }
  #pragma unroll
  for (int i = 0; i < NB; ++i) {           // B: BN*4 slots (512 or 256)
    int s = i * 256 + tid;
    int row = s >> 2, cg = (s & 3) ^ ((s >> 3) & 3);
    boff[i] = (n0 + row) * K + cg * 8;
  }

  f32x4 acc[4][JT];
  #pragma unroll
  for (int i = 0; i < 4; ++i)
    #pragma unroll
    for (int j = 0; j < JT; ++j)
      acc[i][j] = (f32x4){0.f, 0.f, 0.f, 0.f};

  const int NK = K >> 5;

  auto STAGE = [&](int buf, int t) {
    const int k0 = t * 32;
    #pragma unroll
    for (int i = 0; i < 2; ++i)
      gl2lds16(A + aoff[i] + k0, (char*)As[buf] + (size_t)(i * 256 + w * 64) * 16);
    #pragma unroll
    for (int i = 0; i < NB; ++i)
      gl2lds16(Bt + boff[i] + k0, (char*)Bs[buf] + (size_t)(i * 256 + w * 64) * 16);
  };

  // prologue: depth-2
  STAGE(0, 0);
  if (NK > 1) STAGE(1, 1);

  int cur = 0;
  for (int it = 0; it < NK; ++it) {
    if (it + 1 < NK) vmwait<L>(); else vmwait<0>();
    barrier_nodrain();               // tile `it` landed everywhere; buf free
    if (it + 2 < NK) STAGE(cur == 0 ? 2 : cur - 1, it + 2);
    const u16* AsB = As[cur];
    const u16* BsB = Bs[cur];
    bf16x8 af[4], bfr[JT];
    #pragma unroll
    for (int i = 0; i < 4; ++i)
      af[i] = ldb8(&AsB[(wm * 64 + i * 16 + l15) * 32 + ((lq ^ swz2) * 8)]);
    #pragma unroll
    for (int j = 0; j < JT; ++j)
      bfr[j] = ldb8(&BsB[(wn * (BN / 2) + j * 16 + l15) * 32 + ((lq ^ swz2) * 8)]);
    #pragma unroll
    for (int i = 0; i < 4; ++i)
      #pragma unroll
      for (int j = 0; j < JT; ++j)
        acc[i][j] = __builtin_amdgcn_mfma_f32_16x16x32_bf16(af[i], bfr[j], acc[i][j], 0, 0, 0);
    cur = (cur == 2) ? 0 : cur + 1;
  }

  if (MODE == 1 && n0 >= 2048) {
    #pragma unroll
    for (int i = 0; i < 4; ++i) {
      int rowb = m0 + wm * 64 + i * 16 + lq * 4;   // 4 consecutive t
      int b_ = rowb >> 11, t0 = rowb & 2047;
      int tl = t0 & 63;
      int c = tl >> 4, ll = (tl >> 2) & 3;
      int pos0 = (c >> 1) * 32 + ll * 8 + (c & 1) * 4;
      size_t tdst = (size_t)(t0 & ~63) + pos0;
      #pragma unroll
      for (int j = 0; j < JT; ++j) {
        int col = n0 + wn * (BN / 2) + j * 16 + l15;
        int hd = col - 2048;
        float bsv = bias[col];
        u16x4 pk;
        #pragma unroll
        for (int r = 0; r < 4; ++r) pk[r] = f2bf(acc[i][j][r] + bsv);
        *(u16x4*)&Vt[(size_t)(b_ * 1024 + hd) * Tt + tdst] = pk;
      }
    }
  } else {
    const int ldc = (MODE == 1) ? 2048 : N;
    #pragma unroll
    for (int i = 0; i < 4; ++i) {
      int row = m0 + wm * 64 + i * 16 + lq * 4;
      #pragma unroll
      for (int j = 0; j < JT; ++j) {
        int col = n0 + wn * (BN / 2) + j * 16 + l15;
        float bsv = bias[col];
        #pragma unroll
        for (int r = 0; r < 4; ++r) {
          float v = acc[i][j][r] + bsv;
          if (MODE == 1) ((u16*)Cout)[(size_t)(row + r) * ldc + col] = f2bf(v);
          else           ((float*)Cout)[(size_t)(row + r) * ldc + col] = v;
        }
      }
    }
  }
}

// ============ fused causal flash attention — R0 structure + counted-vmcnt ============
// Block = 256 thr = 4 waves, one 64-row q-tile per block (R0's proven-best
// layout: 1024 blocks, balanced heavy/light quads). This round's change: LDS
// K/V TRIPLE-buffered with depth-2 prefetch and counted-vmcnt barriers (see
// gemm_bt comment) -- the measured ~3400cy/iter floor across R0-R3 is the
// depth-1 __syncthreads pipeline's exposed staging latency, invariant to work
// content; giving each staged tile ~2 iterations to land attacks it directly.
// Chain-shortening micro-opts kept from R1-R3: tree-max, permlane32_swap max
// hop, defer-max (THR=8 log2), row-sum l via MFMA ones-trick, native cvt-pack,
// setprio around MFMA clusters.

__device__ __forceinline__ bf16x8 packp(const f32x4& a, const f32x4& b) {
  bf16x8 r;
  #pragma unroll
  for (int i = 0; i < 4; ++i) { r[i] = (__bf16)a[i]; r[i + 4] = (__bf16)b[i]; }
  return r;
}
__device__ __forceinline__ bf16x8 qscale(const u16* p) {
  u16x8 q = *(const u16x8*)p;
  u16x8 s;
  #pragma unroll
  for (int j = 0; j < 8; ++j) s[j] = f2bf(bf2f(q[j]) * SCALE2);
  return __builtin_bit_cast(bf16x8, s);
}

// mask (diagonal only) + row-max + defer-max rescale + exp2; P left in t.
__device__ __forceinline__ void softmax_step(f32x4 (&t)[4], float& m, f32x4 (&o)[4],
                                             f32x4& lacc, bool maskDiag, int kk,
                                             int qg, int lq) {
  if (maskDiag) {
    #pragma unroll
    for (int i = 0; i < 4; ++i)
      #pragma unroll
      for (int r = 0; r < 4; ++r) {
        int kv = kk + i * 16 + lq * 4 + r;
        if (kv > qg) t[i][r] = -__builtin_inff();
      }
  }
  float a0 = fmaxf(fmaxf(t[0][0], t[0][1]), fmaxf(t[0][2], t[0][3]));
  float a1 = fmaxf(fmaxf(t[1][0], t[1][1]), fmaxf(t[1][2], t[1][3]));
  float a2 = fmaxf(fmaxf(t[2][0], t[2][1]), fmaxf(t[2][2], t[2][3]));
  float a3 = fmaxf(fmaxf(t[3][0], t[3][1]), fmaxf(t[3][2], t[3][3]));
  float mx = fmaxf(fmaxf(a0, a1), fmaxf(a2, a3));
  mx = fmaxf(mx, __shfl_xor(mx, 16));
#if __has_builtin(__builtin_amdgcn_permlane32_swap)
  {
    unsigned mu = __builtin_bit_cast(unsigned, mx);
    auto r2 = __builtin_amdgcn_permlane32_swap(mu, mu, false, false);
    mx = fmaxf(__builtin_bit_cast(float, (unsigned)r2[0]),
               __builtin_bit_cast(float, (unsigned)r2[1]));
  }
#else
  mx = fmaxf(mx, __shfl_xor(mx, 32));
#endif
  if (!__all(mx <= m + 8.0f)) {
    float mn = fmaxf(m, mx);
    float al = __builtin_amdgcn_exp2f(m - mn);
    m = mn;
    lacc[0] *= al;   // only element 0 of the l-accumulator is ever read
    #pragma unroll
    for (int jd = 0; jd < 4; ++jd)
      #pragma unroll
      for (int r = 0; r < 4; ++r) o[jd][r] *= al;
  }
  #pragma unroll
  for (int i = 0; i < 4; ++i)
    #pragma unroll
    for (int r = 0; r < 4; ++r)
      t[i][r] = __builtin_amdgcn_exp2f(t[i][r] - m);
}

__global__ __launch_bounds__(256, 3)
void attn_fused(const u16* __restrict__ qk, const u16* __restrict__ vt,
                u16* __restrict__ y) {
  __shared__ u16 Ks[3][64 * 64];    // swizzled [kv-row][d], triple-buffered
  __shared__ u16 Vts[3][64 * 64];   // swizzled [d-row][kv-permuted]
  const int tid = threadIdx.x;
  const int ln = tid & 63, w = tid >> 6;
  const int l15 = ln & 15, lq = ln >> 4;
  const int swz = l15 & 7;
  const int bx = blockIdx.x;
  const int bh = bx & 31;
  const int h  = bh & 15, b = bh >> 4;
  // balanced heavy/light rounds (R0): resident quads sum to ~62 iters
  const int rr_ = bx >> 8, g = (bx >> 5) & 7;
  const int qt = (rr_ == 0) ? 31 - g : (rr_ == 1) ? 16 + g : (rr_ == 2) ? 15 - g : g;
  const int q0w = qt * 64 + w * 16;

  const u16* qbase = qk + (size_t)(b * Tt) * 2048 + h * HD;
  const u16* kbase = qk + (size_t)(b * Tt) * 2048 + 1024 + h * HD;
  const u16* vbase = vt + (size_t)(b * 1024 + h * HD) * Tt;

  // staging: thread handles slots s0=tid, s1=256+tid; row=s>>3, swizzled chunk
  const int s0 = tid, s1 = 256 + tid;
  const int koff0 = (s0 >> 3) * 2048 + (((s0 & 7) ^ ((s0 >> 3) & 7)) * 8);
  const int koff1 = (s1 >> 3) * 2048 + (((s1 & 7) ^ ((s1 >> 3) & 7)) * 8);

  // Q B-fragments (n=q=l15, k=d), prescaled by 1/sqrt(d)*log2e
  const u16* qrA = qbase + (size_t)(q0w + l15) * 2048;
  bf16x8 qA0 = qscale(qrA + lq * 8), qA1 = qscale(qrA + 32 + lq * 8);

  bf16x8 ones;
  #pragma unroll
  for (int j = 0; j < 8; ++j) ones[j] = (__bf16)1.0f;

  f32x4 o[4];
  #pragma unroll
  for (int j = 0; j < 4; ++j) o[j] = (f32x4){0, 0, 0, 0};
  f32x4 lacc = (f32x4){0, 0, 0, 0};
  float m = -__builtin_inff();
  const int qg = q0w + l15;
  const int nkv = qt + 1;

  auto STAGE = [&](int buf, int t) {
    const u16* ks = kbase + (size_t)(t * 64) * 2048;
    const u16* vs = vbase + t * 64;
    gl2lds16(ks + koff0, (char*)Ks[buf] + w * 1024);
    gl2lds16(ks + koff1, (char*)Ks[buf] + 4096 + w * 1024);
    gl2lds16(vs + koff0, (char*)Vts[buf] + w * 1024);
    gl2lds16(vs + koff1, (char*)Vts[buf] + 4096 + w * 1024);
  };

  // prologue: depth-2
  STAGE(0, 0);
  if (nkv > 1) STAGE(1, 1);

  int cur = 0;
  for (int it = 0; it < nkv; ++it) {
    const int kk = it * 64;
    if (it + 1 < nkv) vmwait<4>(); else vmwait<0>();
    barrier_nodrain();               // tile `it` landed everywhere; buf free
    if (it + 2 < nkv) STAGE(cur == 0 ? 2 : cur - 1, it + 2);
    const u16* KsB  = Ks[cur];
    const u16* VtsB = Vts[cur];

    // S^T = K * Q^T
    f32x4 t[4];
    #pragma unroll
    for (int i = 0; i < 4; ++i) t[i] = (f32x4){0, 0, 0, 0};
    __builtin_amdgcn_s_setprio(1);
    #pragma unroll
    for (int i = 0; i < 4; ++i) {
      bf16x8 kf0 = ldb8(&KsB[(i * 16 + l15) * 64 + ((lq    ) ^ swz) * 8]);
      bf16x8 kf1 = ldb8(&KsB[(i * 16 + l15) * 64 + ((lq + 4) ^ swz) * 8]);
      t[i] = __builtin_amdgcn_mfma_f32_16x16x32_bf16(kf0, qA0, t[i], 0, 0, 0);
      t[i] = __builtin_amdgcn_mfma_f32_16x16x32_bf16(kf1, qA1, t[i], 0, 0, 0);
    }
    __builtin_amdgcn_s_setprio(0);

    // online softmax (log2 domain); state per q = per lane (l15)
    softmax_step(t, m, o, lacc, it == nkv - 1, kk, qg, lq);
    bf16x8 p0 = packp(t[0], t[1]), p1 = packp(t[2], t[3]);

    // O^T += V^T * P ; l += ones * P (row-sum via MFMA, no cross-lane sum)
    __builtin_amdgcn_s_setprio(1);
    #pragma unroll
    for (int mf = 0; mf < 2; ++mf) {
      bf16x8 pbv = mf ? p1 : p0;
      lacc = __builtin_amdgcn_mfma_f32_16x16x32_bf16(ones, pbv, lacc, 0, 0, 0);
      #pragma unroll
      for (int jd = 0; jd < 4; ++jd) {
        int d = jd * 16 + l15;
        bf16x8 vf = ldb8(&VtsB[d * 64 + ((mf * 4 + lq) ^ swz) * 8]);
        o[jd] = __builtin_amdgcn_mfma_f32_16x16x32_bf16(vf, pbv, o[jd], 0, 0, 0);
      }
    }
    __builtin_amdgcn_s_setprio(0);
    cur = (cur == 2) ? 0 : cur + 1;
  }

  // epilogue: per-lane normalize, store O^T[d][q] -> y[q][d] as u16x4 runs
  float inv = 1.f / lacc[0];
  const size_t ybase = (size_t)(b * Tt + q0w + l15) * Cc + h * HD;
  #pragma unroll
  for (int jd = 0; jd < 4; ++jd) {
    u16x4 pk;
    #pragma unroll
    for (int r = 0; r < 4; ++r) pk[r] = f2bf(o[jd][r] * inv);
    *(u16x4*)&y[ybase + jd * 16 + lq * 4] = pk;
  }
}

extern "C" void kernel_launch(void* const* d_in, const int* in_sizes, int n_in,
                              void* d_out, int out_size, void* d_ws, size_t ws_size,
                              hipStream_t stream) {
  const float* x      = (const float*)d_in[0];
  const float* w_attn = (const float*)d_in[1];
  const float* b_attn = (const float*)d_in[2];
  const float* w_proj = (const float*)d_in[3];
  const float* b_proj = (const float*)d_in[4];
  float* out = (float*)d_out;

  char* ws = (char*)d_ws;
  u16* xb  = (u16*)(ws + 0);          // 4096x1024 bf16   (8 MB)
  u16* wat = (u16*)(ws + 8388608);    // 3072x1024 bf16   (6 MB)   w_attn^T
  u16* wpt = (u16*)(ws + 14680064);   // 1024x1024 bf16   (2 MB)   w_proj^T
  u16* qkb = (u16*)(ws + 16777216);   // 4096x2048 bf16   (16 MB)  Q,K
  u16* vtb = (u16*)(ws + 33554432);   // 2048x2048 bf16   (8 MB)   V^T (permuted)
  u16* yb  = (u16*)(ws + 41943040);   // 4096x1024 bf16   (8 MB)

  prep_kernel<<<5120, 256, 0, stream>>>(x, w_attn, w_proj, xb, wat, wpt);
  gemm_bt<1, 128, 3><<<dim3(24, 32), 256, 0, stream>>>(xb, wat, b_attn, (void*)qkb, vtb, 4096, 3072, 1024);
  attn_fused<<<1024, 256, 0, stream>>>(qkb, vtb, yb);
  gemm_bt<0, 64, 4><<<dim3(16, 32), 256, 0, stream>>>(yb, wpt, b_proj, (void*)out, nullptr, 4096, 1024, 1024);
}

// Round 5
// 171.893 us; speedup vs baseline: 1.0859x; 1.0150x over previous
//
#include <hip/hip_runtime.h>
#include <stdint.h>

#define Bb 2
#define Tt 2048
#define Cc 1024
#define Hh 16
#define HD 64
#define C3 3072

typedef __bf16 bf16x8 __attribute__((ext_vector_type(8)));
typedef float  f32x4  __attribute__((ext_vector_type(4)));
typedef unsigned short u16;
typedef u16 u16x8 __attribute__((ext_vector_type(8)));
typedef u16 u16x4 __attribute__((ext_vector_type(4)));

#define SCALE2 0.18033688f  /* 1/sqrt(64) * log2(e) */

__device__ __forceinline__ u16 f2bf(float f) {
  union { float f; unsigned u; } v; v.f = f;
  return (u16)((v.u + 0x7fffu + ((v.u >> 16) & 1u)) >> 16);  // RNE
}
__device__ __forceinline__ float bf2f(u16 a) {
  union { unsigned u; float f; } v; v.u = ((unsigned)a) << 16; return v.f;
}

// async global->LDS, 16B per lane. LDS dest = wave-uniform base + lane*16.
__device__ __forceinline__ void gl2lds16(const void* g, void* s) {
  __builtin_amdgcn_global_load_lds(
      (__attribute__((address_space(1))) void*)(g),
      (__attribute__((address_space(3))) void*)(s), 16, 0, 0);
}

__device__ __forceinline__ bf16x8 ldb8(const u16* p) {
  return __builtin_bit_cast(bf16x8, *(const u16x8*)p);
}

// counted vmcnt wait: allow N of this wave's VMEM ops to stay in flight.
template <int N>
__device__ __forceinline__ void vmwait() {
  asm volatile("s_waitcnt vmcnt(%0)" :: "n"(N) : "memory");
}
// barrier WITHOUT the compiler's vmcnt(0) drain (raw s_barrier); sched_barrier
// pins ds_reads below it.
__device__ __forceinline__ void barrier_nodrain() {
  __builtin_amdgcn_s_barrier();
  __builtin_amdgcn_sched_barrier(0);
}

// ---------------- merged prep: cvt_x + w_attn^T + w_proj^T ----------------
__global__ __launch_bounds__(256)
void prep_kernel(const float* __restrict__ x, const float* __restrict__ w_attn,
                 const float* __restrict__ w_proj, u16* __restrict__ xb,
                 u16* __restrict__ wat, u16* __restrict__ wpt) {
  __shared__ u16 tile[64][65];
  const int blk = blockIdx.x;
  const int tid = threadIdx.x;
  if (blk < 4096) {
    int i = blk * 256 + tid;
    float4 v = ((const float4*)x)[i];
    u16x4 o = { f2bf(v.x), f2bf(v.y), f2bf(v.z), f2bf(v.w) };
    ((u16x4*)xb)[i] = o;
    return;
  }
  const float* in; u16* out; int R, C, c0, r0;
  if (blk < 4096 + 768) {
    int t = blk - 4096;
    in = w_attn; out = wat; R = 1024; C = 3072;
    c0 = (t % 48) * 64; r0 = (t / 48) * 64;
  } else {
    int t = blk - 4864;
    in = w_proj; out = wpt; R = 1024; C = 1024;
    c0 = (t & 15) * 64; r0 = (t >> 4) * 64;
  }
  int xx = tid & 63, yy = tid >> 6;
  #pragma unroll
  for (int rr = yy; rr < 64; rr += 4)
    tile[rr][xx] = f2bf(in[(size_t)(r0 + rr) * C + c0 + xx]);
  __syncthreads();
  #pragma unroll
  for (int rr = yy; rr < 64; rr += 4)
    out[(size_t)(c0 + rr) * R + r0 + xx] = tile[xx][rr];
}

// ---------------- bf16 GEMM: C[M][N] = A[M][K] * Bt[N][K]^T + bias ----------------
// (unchanged from round 4: triple-buffered, depth-2 prefetch, counted vmcnt)
template <int MODE, int BN, int MINW>
__global__ __launch_bounds__(256, MINW)
void gemm_bt(const u16* __restrict__ A, const u16* __restrict__ Bt,
             const float* __restrict__ bias, void* __restrict__ Cout,
             u16* __restrict__ Vt, int M, int N, int K) {
  __shared__ u16 As[3][128 * 32];
  __shared__ u16 Bs[3][BN * 32];
  constexpr int JT = BN / 32;          // j-tiles per wave
  constexpr int NB = BN / 128 + 1;     // B staging instrs per thread
  constexpr int L  = 2 + NB;           // loads in flight per thread per tile
  const int tid = threadIdx.x;
  const int ln  = tid & 63;
  const int w   = tid >> 6;
  const int wm  = w >> 1, wn = w & 1;
  const int l15 = ln & 15, lq = ln >> 4;
  const int swz2 = (l15 >> 1) & 3;
  const int m0 = blockIdx.y * 128, n0 = blockIdx.x * BN;

  int aoff[2], boff[NB];
  #pragma unroll
  for (int i = 0; i < 2; ++i) {
    int s = i * 256 + tid;                 // A: 512 slots
    int row = s >> 2, cg = (s & 3) ^ ((s >> 3) & 3);
    aoff[i] = (m0 + row) * K + cg * 8;
  }
  #pragma unroll
  for (int i = 0; i < NB; ++i) {           // B: BN*4 slots (512 or 256)
    int s = i * 256 + tid;
    int row = s >> 2, cg = (s & 3) ^ ((s >> 3) & 3);
    boff[i] = (n0 + row) * K + cg * 8;
  }

  f32x4 acc[4][JT];
  #pragma unroll
  for (int i = 0; i < 4; ++i)
    #pragma unroll
    for (int j = 0; j < JT; ++j)
      acc[i][j] = (f32x4){0.f, 0.f, 0.f, 0.f};

  const int NK = K >> 5;

  auto STAGE = [&](int buf, int t) {
    const int k0 = t * 32;
    #pragma unroll
    for (int i = 0; i < 2; ++i)
      gl2lds16(A + aoff[i] + k0, (char*)As[buf] + (size_t)(i * 256 + w * 64) * 16);
    #pragma unroll
    for (int i = 0; i < NB; ++i)
      gl2lds16(Bt + boff[i] + k0, (char*)Bs[buf] + (size_t)(i * 256 + w * 64) * 16);
  };

  // prologue: depth-2
  STAGE(0, 0);
  if (NK > 1) STAGE(1, 1);

  int cur = 0;
  for (int it = 0; it < NK; ++it) {
    if (it + 1 < NK) vmwait<L>(); else vmwait<0>();
    barrier_nodrain();               // tile `it` landed everywhere; buf free
    if (it + 2 < NK) STAGE(cur == 0 ? 2 : cur - 1, it + 2);
    const u16* AsB = As[cur];
    const u16* BsB = Bs[cur];
    bf16x8 af[4], bfr[JT];
    #pragma unroll
    for (int i = 0; i < 4; ++i)
      af[i] = ldb8(&AsB[(wm * 64 + i * 16 + l15) * 32 + ((lq ^ swz2) * 8)]);
    #pragma unroll
    for (int j = 0; j < JT; ++j)
      bfr[j] = ldb8(&BsB[(wn * (BN / 2) + j * 16 + l15) * 32 + ((lq ^ swz2) * 8)]);
    #pragma unroll
    for (int i = 0; i < 4; ++i)
      #pragma unroll
      for (int j = 0; j < JT; ++j)
        acc[i][j] = __builtin_amdgcn_mfma_f32_16x16x32_bf16(af[i], bfr[j], acc[i][j], 0, 0, 0);
    cur = (cur == 2) ? 0 : cur + 1;
  }

  if (MODE == 1 && n0 >= 2048) {
    #pragma unroll
    for (int i = 0; i < 4; ++i) {
      int rowb = m0 + wm * 64 + i * 16 + lq * 4;   // 4 consecutive t
      int b_ = rowb >> 11, t0 = rowb & 2047;
      int tl = t0 & 63;
      int c = tl >> 4, ll = (tl >> 2) & 3;
      int pos0 = (c >> 1) * 32 + ll * 8 + (c & 1) * 4;
      size_t tdst = (size_t)(t0 & ~63) + pos0;
      #pragma unroll
      for (int j = 0; j < JT; ++j) {
        int col = n0 + wn * (BN / 2) + j * 16 + l15;
        int hd = col - 2048;
        float bsv = bias[col];
        u16x4 pk;
        #pragma unroll
        for (int r = 0; r < 4; ++r) pk[r] = f2bf(acc[i][j][r] + bsv);
        *(u16x4*)&Vt[(size_t)(b_ * 1024 + hd) * Tt + tdst] = pk;
      }
    }
  } else {
    const int ldc = (MODE == 1) ? 2048 : N;
    #pragma unroll
    for (int i = 0; i < 4; ++i) {
      int row = m0 + wm * 64 + i * 16 + lq * 4;
      #pragma unroll
      for (int j = 0; j < JT; ++j) {
        int col = n0 + wn * (BN / 2) + j * 16 + l15;
        float bsv = bias[col];
        #pragma unroll
        for (int r = 0; r < 4; ++r) {
          float v = acc[i][j][r] + bsv;
          if (MODE == 1) ((u16*)Cout)[(size_t)(row + r) * ldc + col] = f2bf(v);
          else           ((float*)Cout)[(size_t)(row + r) * ldc + col] = v;
        }
      }
    }
  }
}

// ============ fused causal flash attention — KVBLK=128, O^T ============
// R0-R4 measured law: per-barrier-iteration wall time ~3400cy, nearly invariant
// to the work inside the iteration (R3: 2x work -> +15%); nothing saturated
// (VALU<=46%, MFMA 14%, LDS ~38%). The cost scales with the NUMBER of serial
// online-softmax state updates + barriers. So: double the KV tile to 128 --
// heavy block 32 -> 16 iterations, one max/exp/rescale pass per 128 kv instead
// of per 64. The V^T kv-permutation written by gemm1 is 32-block-local, so it
// composes unchanged into the 4 PV k-slots per 128-tile (chunk index ks*4+lq).
// LDS 2x(16+16)KB = 64KB -> 2 blocks/CU; each wave carries 2x intra-iter ILP.
// V-row swizzle widens to 4-bit XOR (16 chunks of 16B per 256B row; staging
// uses the matching inverse). Double-buffered with plain __syncthreads: R4
// showed the pre-barrier drain is free (prefetch has a full iteration to land).
// Micro-opts kept: tree-max, permlane32_swap hop, defer-max (THR=8, log2),
// row-sum l via MFMA-ones, native cvt-pack, setprio around MFMA clusters.

__device__ __forceinline__ bf16x8 packp(const f32x4& a, const f32x4& b) {
  bf16x8 r;
  #pragma unroll
  for (int i = 0; i < 4; ++i) { r[i] = (__bf16)a[i]; r[i + 4] = (__bf16)b[i]; }
  return r;
}
__device__ __forceinline__ bf16x8 qscale(const u16* p) {
  u16x8 q = *(const u16x8*)p;
  u16x8 s;
  #pragma unroll
  for (int j = 0; j < 8; ++j) s[j] = f2bf(bf2f(q[j]) * SCALE2);
  return __builtin_bit_cast(bf16x8, s);
}

__global__ __launch_bounds__(256, 2)
void attn_fused(const u16* __restrict__ qk, const u16* __restrict__ vt,
                u16* __restrict__ y) {
  __shared__ u16 Ks[2][128 * 64];   // swizzled [kv-row][d], double-buffered
  __shared__ u16 Vts[2][64 * 128];  // swizzled [d-row][kv-permuted]
  const int tid = threadIdx.x;
  const int ln = tid & 63, w = tid >> 6;
  const int l15 = ln & 15, lq = ln >> 4;
  const int swzK = l15 & 7;
  const int bx = blockIdx.x;
  const int bh = bx & 31;
  const int h  = bh & 15, b = bh >> 4;
  // balanced heavy/light rounds (R0 pattern)
  const int rr_ = bx >> 8, g = (bx >> 5) & 7;
  const int qt = (rr_ == 0) ? 31 - g : (rr_ == 1) ? 16 + g : (rr_ == 2) ? 15 - g : g;
  const int q0w = qt * 64 + w * 16;

  const u16* qbase = qk + (size_t)(b * Tt) * 2048 + h * HD;
  const u16* kbase = qk + (size_t)(b * Tt) * 2048 + 1024 + h * HD;
  const u16* vbase = vt + (size_t)(b * 1024 + h * HD) * Tt;

  // staging offsets: K tile 128x64 (8 chunks/row), V tile 64x128 (16 chunks/row)
  int koff[4], voff[4];
  #pragma unroll
  for (int i = 0; i < 4; ++i) {
    int s = i * 256 + tid;
    koff[i] = (s >> 3) * 2048 + (((s & 7) ^ ((s >> 3) & 7)) * 8);
    voff[i] = (s >> 4) * Tt + (((s & 15) ^ ((s >> 4) & 15)) * 8);
  }

  // Q B-fragments (n=q=l15, k=d), prescaled by 1/sqrt(d)*log2e
  const u16* qrA = qbase + (size_t)(q0w + l15) * 2048;
  bf16x8 qA0 = qscale(qrA + lq * 8), qA1 = qscale(qrA + 32 + lq * 8);

  bf16x8 ones;
  #pragma unroll
  for (int j = 0; j < 8; ++j) ones[j] = (__bf16)1.0f;

  f32x4 o[4];
  #pragma unroll
  for (int j = 0; j < 4; ++j) o[j] = (f32x4){0, 0, 0, 0};
  f32x4 lacc = (f32x4){0, 0, 0, 0};
  float m = -__builtin_inff();
  const int qg = q0w + l15;
  const int nkv = (qt >> 1) + 1;    // 128-wide kv tiles

  auto STAGE = [&](int buf, int t) {
    const u16* ks = kbase + (size_t)(t * 128) * 2048;
    const u16* vs = vbase + t * 128;
    #pragma unroll
    for (int i = 0; i < 4; ++i) {
      gl2lds16(ks + koff[i], (char*)Ks[buf] + (size_t)(i * 256 + w * 64) * 16);
      gl2lds16(vs + voff[i], (char*)Vts[buf] + (size_t)(i * 256 + w * 64) * 16);
    }
  };

  STAGE(0, 0);
  int cur = 0;
  for (int it = 0; it < nkv; ++it) {
    const int kk = it * 128;
    __syncthreads();                 // tile `it` landed; buf cur^1 readers done
    if (it + 1 < nkv) STAGE(cur ^ 1, it + 1);
    const u16* KsB  = Ks[cur];
    const u16* VtsB = Vts[cur];

    // S^T = K * Q^T : 128 kv rows = 8 row-subtiles x 2 k-halves
    f32x4 t[8];
    #pragma unroll
    for (int i = 0; i < 8; ++i) t[i] = (f32x4){0, 0, 0, 0};
    __builtin_amdgcn_s_setprio(1);
    #pragma unroll
    for (int i = 0; i < 8; ++i) {
      bf16x8 kf0 = ldb8(&KsB[(i * 16 + l15) * 64 + ((lq      ^ swzK) * 8)]);
      bf16x8 kf1 = ldb8(&KsB[(i * 16 + l15) * 64 + (((lq + 4) ^ swzK) * 8)]);
      t[i] = __builtin_amdgcn_mfma_f32_16x16x32_bf16(kf0, qA0, t[i], 0, 0, 0);
      t[i] = __builtin_amdgcn_mfma_f32_16x16x32_bf16(kf1, qA1, t[i], 0, 0, 0);
    }
    __builtin_amdgcn_s_setprio(0);

    // causal mask on the last tile (covers the diagonal; for even qt the upper
    // 64 kv of this tile are fully masked per-element)
    if (it == nkv - 1) {
      #pragma unroll
      for (int i = 0; i < 8; ++i)
        #pragma unroll
        for (int r = 0; r < 4; ++r) {
          int kv = kk + i * 16 + lq * 4 + r;
          if (kv > qg) t[i][r] = -__builtin_inff();
        }
    }

    // online softmax (log2 domain); tree max over 32 values (depth 5)
    float a0 = fmaxf(fmaxf(t[0][0], t[0][1]), fmaxf(t[0][2], t[0][3]));
    float a1 = fmaxf(fmaxf(t[1][0], t[1][1]), fmaxf(t[1][2], t[1][3]));
    float a2 = fmaxf(fmaxf(t[2][0], t[2][1]), fmaxf(t[2][2], t[2][3]));
    float a3 = fmaxf(fmaxf(t[3][0], t[3][1]), fmaxf(t[3][2], t[3][3]));
    float a4 = fmaxf(fmaxf(t[4][0], t[4][1]), fmaxf(t[4][2], t[4][3]));
    float a5 = fmaxf(fmaxf(t[5][0], t[5][1]), fmaxf(t[5][2], t[5][3]));
    float a6 = fmaxf(fmaxf(t[6][0], t[6][1]), fmaxf(t[6][2], t[6][3]));
    float a7 = fmaxf(fmaxf(t[7][0], t[7][1]), fmaxf(t[7][2], t[7][3]));
    float mx = fmaxf(fmaxf(fmaxf(a0, a1), fmaxf(a2, a3)),
                     fmaxf(fmaxf(a4, a5), fmaxf(a6, a7)));
    mx = fmaxf(mx, __shfl_xor(mx, 16));
#if __has_builtin(__builtin_amdgcn_permlane32_swap)
    {
      unsigned mu = __builtin_bit_cast(unsigned, mx);
      auto r2 = __builtin_amdgcn_permlane32_swap(mu, mu, false, false);
      mx = fmaxf(__builtin_bit_cast(float, (unsigned)r2[0]),
                 __builtin_bit_cast(float, (unsigned)r2[1]));
    }
#else
    mx = fmaxf(mx, __shfl_xor(mx, 32));
#endif

    // defer-max: rescale only when the wave's max grew by > 8 (log2 units)
    if (!__all(mx <= m + 8.0f)) {
      float mn = fmaxf(m, mx);
      float al = __builtin_amdgcn_exp2f(m - mn);
      m = mn;
      lacc[0] *= al;   // only element 0 is ever read
      #pragma unroll
      for (int jd = 0; jd < 4; ++jd)
        #pragma unroll
        for (int r = 0; r < 4; ++r) o[jd][r] *= al;
    }
    #pragma unroll
    for (int i = 0; i < 8; ++i)
      #pragma unroll
      for (int r = 0; r < 4; ++r)
        t[i][r] = __builtin_amdgcn_exp2f(t[i][r] - m);

    // P -> bf16 fragments: pk_[ks] covers kv slot ks*32..+31 (permuted order)
    bf16x8 pk_[4];
    #pragma unroll
    for (int ks = 0; ks < 4; ++ks) pk_[ks] = packp(t[2 * ks], t[2 * ks + 1]);

    // O^T += V^T * P ; l += ones * P (row-sum via MFMA). 4 k-slots per tile.
    __builtin_amdgcn_s_setprio(1);
    #pragma unroll
    for (int ks = 0; ks < 4; ++ks) {
      lacc = __builtin_amdgcn_mfma_f32_16x16x32_bf16(ones, pk_[ks], lacc, 0, 0, 0);
      #pragma unroll
      for (int jd = 0; jd < 4; ++jd) {
        int d = jd * 16 + l15;
        bf16x8 vf = ldb8(&VtsB[d * 128 + (((ks * 4 + lq) ^ l15) * 8)]);
        o[jd] = __builtin_amdgcn_mfma_f32_16x16x32_bf16(vf, pk_[ks], o[jd], 0, 0, 0);
      }
    }
    __builtin_amdgcn_s_setprio(0);
    cur ^= 1;
  }

  // epilogue: per-lane normalize, store O^T[d][q] -> y[q][d] as u16x4 runs
  float inv = 1.f / lacc[0];
  const size_t ybase = (size_t)(b * Tt + q0w + l15) * Cc + h * HD;
  #pragma unroll
  for (int jd = 0; jd < 4; ++jd) {
    u16x4 pk;
    #pragma unroll
    for (int r = 0; r < 4; ++r) pk[r] = f2bf(o[jd][r] * inv);
    *(u16x4*)&y[ybase + jd * 16 + lq * 4] = pk;
  }
}

extern "C" void kernel_launch(void* const* d_in, const int* in_sizes, int n_in,
                              void* d_out, int out_size, void* d_ws, size_t ws_size,
                              hipStream_t stream) {
  const float* x      = (const float*)d_in[0];
  const float* w_attn = (const float*)d_in[1];
  const float* b_attn = (const float*)d_in[2];
  const float* w_proj = (const float*)d_in[3];
  const float* b_proj = (const float*)d_in[4];
  float* out = (float*)d_out;

  char* ws = (char*)d_ws;
  u16* xb  = (u16*)(ws + 0);          // 4096x1024 bf16   (8 MB)
  u16* wat = (u16*)(ws + 8388608);    // 3072x1024 bf16   (6 MB)   w_attn^T
  u16* wpt = (u16*)(ws + 14680064);   // 1024x1024 bf16   (2 MB)   w_proj^T
  u16* qkb = (u16*)(ws + 16777216);   // 4096x2048 bf16   (16 MB)  Q,K
  u16* vtb = (u16*)(ws + 33554432);   // 2048x2048 bf16   (8 MB)   V^T (permuted)
  u16* yb  = (u16*)(ws + 41943040);   // 4096x1024 bf16   (8 MB)

  prep_kernel<<<5120, 256, 0, stream>>>(x, w_attn, w_proj, xb, wat, wpt);
  gemm_bt<1, 128, 3><<<dim3(24, 32), 256, 0, stream>>>(xb, wat, b_attn, (void*)qkb, vtb, 4096, 3072, 1024);
  attn_fused<<<1024, 256, 0, stream>>>(qkb, vtb, yb);
  gemm_bt<0, 64, 4><<<dim3(16, 32), 256, 0, stream>>>(yb, wpt, b_proj, (void*)out, nullptr, 4096, 1024, 1024);
}